// Round 4
// baseline (467.699 us; speedup 1.0000x reference)
//
#include <hip/hip_runtime.h>
#include <stdint.h>

#define SEQ   2048
#define BATCH 4
#define NH    16
#define HD    64
#define DIMN  1024
#define MROWS (BATCH*SEQ)   // 8192

typedef __attribute__((ext_vector_type(8))) short          bf16x8;
typedef __attribute__((ext_vector_type(8))) unsigned short ushort8;
typedef __attribute__((ext_vector_type(4))) float          f32x4;

static __device__ __forceinline__ unsigned short f2bf(float f) {
    unsigned int u = __builtin_bit_cast(unsigned int, f);
    u += 0x7fffu + ((u >> 16) & 1u);          // RNE
    return (unsigned short)(u >> 16);
}
// RNE-ish (round-half-up) pack: 3 ops
static __device__ __forceinline__ unsigned int pack2bf(float lo, float hi) {
    unsigned int a = __builtin_bit_cast(unsigned int, lo) + 0x8000u;
    unsigned int b = __builtin_bit_cast(unsigned int, hi) + 0x8000u;
    return __builtin_amdgcn_perm(b, a, 0x07060302u);
}
// truncating pack: 1 op (P in [0,1], rel err <= 2^-8, fine for softmax weights)
static __device__ __forceinline__ unsigned int pack2bf_trunc(float lo, float hi) {
    return __builtin_amdgcn_perm(__builtin_bit_cast(unsigned int, hi),
                                 __builtin_bit_cast(unsigned int, lo), 0x07060302u);
}

// ---------------------------------------------------------------- cast fp32 -> bf16
__global__ __launch_bounds__(256) void cast_bf16_kernel(const float* __restrict__ src,
                                                        unsigned short* __restrict__ dst, int n) {
    int i = (blockIdx.x * 256 + threadIdx.x) * 8;
    if (i >= n) return;
    float4 a = *(const float4*)(src + i);
    float4 b = *(const float4*)(src + i + 4);
    ushort8 o;
    o[0]=f2bf(a.x); o[1]=f2bf(a.y); o[2]=f2bf(a.z); o[3]=f2bf(a.w);
    o[4]=f2bf(b.x); o[5]=f2bf(b.y); o[6]=f2bf(b.z); o[7]=f2bf(b.w);
    *(ushort8*)(dst + i) = o;
}

__global__ __launch_bounds__(256) void cast4_kernel(const float* __restrict__ s0, const float* __restrict__ s1,
                                                    const float* __restrict__ s2, const float* __restrict__ s3,
                                                    unsigned short* __restrict__ d0, unsigned short* __restrict__ d1,
                                                    unsigned short* __restrict__ d2, unsigned short* __restrict__ d3) {
    const float* s; unsigned short* d;
    switch (blockIdx.y) {
        case 0:  s = s0; d = d0; break;
        case 1:  s = s1; d = d1; break;
        case 2:  s = s2; d = d2; break;
        default: s = s3; d = d3; break;
    }
    int i = (blockIdx.x * 256 + threadIdx.x) * 8;
    float4 a = *(const float4*)(s + i);
    float4 b = *(const float4*)(s + i + 4);
    ushort8 o;
    o[0]=f2bf(a.x); o[1]=f2bf(a.y); o[2]=f2bf(a.z); o[3]=f2bf(a.w);
    o[4]=f2bf(b.x); o[5]=f2bf(b.y); o[6]=f2bf(b.z); o[7]=f2bf(b.w);
    *(ushort8*)(d + i) = o;
}

// ---------------------------------------------------------------- RoPE tables (fp32, matches ref)
__global__ __launch_bounds__(256) void rope_tables_kernel(float* __restrict__ cosT,
                                                          float* __restrict__ sinT) {
    int idx = blockIdx.x * 256 + threadIdx.x;     // SEQ*32
    int s = idx >> 5, j = idx & 31;
    float t = (float)(2 * j) / 64.0f;
    float freq = 1.0f / powf(10000.0f, t);
    float ang  = (float)s * freq;
    cosT[idx] = cosf(ang);
    sinT[idx] = sinf(ang);
}

// ---------------------------------------------------------------- mask -> u64 bitmask per 64-key tile
__global__ __launch_bounds__(128) void mask64_kernel(const unsigned char* __restrict__ mask,
                                                     unsigned long long* __restrict__ m64) {
    int t = threadIdx.x;                 // 128 = BATCH * (SEQ/64)
    int b = t >> 5, kt = t & 31;
    const unsigned char* p = mask + b * SEQ + kt * 64;
    unsigned long long v = 0;
    for (int j = 0; j < 64; j++) v |= (unsigned long long)(p[j] != 0) << j;
    m64[t] = v;
}

// ---------------------------------------------------------------- fused Q,K,V^T GEMM
// blockIdx.x: [0..7]=Q, [8..15]=K (both +RoPE, out [B,H,S,D]), [16..23]=V^T
// (out [B,H,D,S]). Q pre-scaled by 0.125*log2e for exp2-domain softmax.
__global__ __launch_bounds__(256) void gemm_qkvt(const unsigned short* __restrict__ X,
        const unsigned short* __restrict__ Wq, const unsigned short* __restrict__ Wk,
        const unsigned short* __restrict__ Wv,
        const float* __restrict__ bq, const float* __restrict__ bk, const float* __restrict__ bv,
        unsigned short* __restrict__ Qo, unsigned short* __restrict__ Ko, unsigned short* __restrict__ Vto,
        const float* __restrict__ cosT, const float* __restrict__ sinT) {
    __shared__ __align__(16) unsigned short As[128 * 32];
    __shared__ __align__(16) unsigned short Bs[128 * 32];
    const int which = blockIdx.x >> 3;
    const int tid  = threadIdx.x;
    const int wid  = tid >> 6, lane = tid & 63;
    const int quad = lane >> 4, l15 = lane & 15;
    const int wm   = wid >> 1,  wn  = wid & 1;

    // A rows (m), B rows (n) in global
    const unsigned short *Ag, *Bg;
    int m0, n0;
    if (which < 2) {
        m0 = blockIdx.y * 128;                 // token rows
        n0 = (blockIdx.x & 7) * 128;           // embed cols
        Ag = X;  Bg = which == 0 ? Wq : Wk;
    } else {
        m0 = (blockIdx.x & 7) * 128;           // e rows
        n0 = blockIdx.y * 128;                 // token rows
        Ag = Wv; Bg = X;
    }

    f32x4 acc[4][4];
#pragma unroll
    for (int i = 0; i < 4; i++)
#pragma unroll
        for (int j = 0; j < 4; j++) acc[i][j] = (f32x4)0.0f;

    const int rb = wid * 32 + (lane >> 2);
    const int cb = (lane & 3) * 8;

    for (int k0 = 0; k0 < DIMN; k0 += 32) {
#pragma unroll
        for (int i = 0; i < 2; i++) {
            const unsigned short* ga = Ag + (size_t)(m0 + rb + i * 16) * DIMN + k0 + cb;
            __builtin_amdgcn_global_load_lds((const __attribute__((address_space(1))) void*)ga,
                (__attribute__((address_space(3))) void*)&As[(wid * 32 + i * 16) * 32], 16, 0, 0);
            const unsigned short* gb = Bg + (size_t)(n0 + rb + i * 16) * DIMN + k0 + cb;
            __builtin_amdgcn_global_load_lds((const __attribute__((address_space(1))) void*)gb,
                (__attribute__((address_space(3))) void*)&Bs[(wid * 32 + i * 16) * 32], 16, 0, 0);
        }
        __syncthreads();
        bf16x8 af[4], bfr[4];
#pragma unroll
        for (int f = 0; f < 4; f++) af[f]  = *(const bf16x8*)&As[(wm * 64 + f * 16 + l15) * 32 + quad * 8];
#pragma unroll
        for (int f = 0; f < 4; f++) bfr[f] = *(const bf16x8*)&Bs[(wn * 64 + f * 16 + l15) * 32 + quad * 8];
#pragma unroll
        for (int fm = 0; fm < 4; fm++)
#pragma unroll
            for (int fn = 0; fn < 4; fn++)
                acc[fm][fn] = __builtin_amdgcn_mfma_f32_16x16x32_bf16(af[fm], bfr[fn], acc[fm][fn], 0, 0, 0);
        __syncthreads();
    }

    if (which < 2) {                            // Q or K: +bias, scale, RoPE, [B,H,S,D]
        const float* bias   = which == 0 ? bq : bk;
        unsigned short* Out = which == 0 ? Qo : Ko;
        const float scale = which == 0 ? 0.18033688011112042f : 1.0f;  // 0.125*log2e
        float bv4[4];
#pragma unroll
        for (int fn = 0; fn < 4; fn++) bv4[fn] = bias[n0 + wn * 64 + fn * 16 + l15];
        const int h = (n0 >> 6) + wn;
#pragma unroll
        for (int fm = 0; fm < 4; fm++)
#pragma unroll
            for (int r = 0; r < 4; r++) {
                int mrow = m0 + wm * 64 + fm * 16 + quad * 4 + r;
                int b = mrow >> 11, s = mrow & (SEQ - 1);
                unsigned short* orow = Out + ((size_t)(b * NH + h) * SEQ + s) * HD;
                float v0 = (acc[fm][0][r] + bv4[0]) * scale;
                float v1 = (acc[fm][1][r] + bv4[1]) * scale;
                float v2 = (acc[fm][2][r] + bv4[2]) * scale;
                float v3 = (acc[fm][3][r] + bv4[3]) * scale;
                int d0 = l15, d1 = 16 + l15;
                float c0 = cosT[s * 32 + d0], s0 = sinT[s * 32 + d0];
                float c1 = cosT[s * 32 + d1], s1 = sinT[s * 32 + d1];
                orow[d0]      = f2bf(v0 * c0 - v2 * s0);
                orow[d0 + 32] = f2bf(v0 * s0 + v2 * c0);
                orow[d1]      = f2bf(v1 * c1 - v3 * s1);
                orow[d1 + 32] = f2bf(v1 * s1 + v3 * c1);
            }
    } else {                                    // V^T: [B,H,D,S]
        float4 bb[4];
#pragma unroll
        for (int fm = 0; fm < 4; fm++)
            bb[fm] = *(const float4*)&bv[m0 + wm * 64 + fm * 16 + quad * 4];
        const int b     = n0 >> 11;
        const int sbase = (n0 & (SEQ - 1)) + wn * 64 + l15;
#pragma unroll
        for (int fm = 0; fm < 4; fm++)
#pragma unroll
            for (int r = 0; r < 4; r++) {
                int e = m0 + wm * 64 + fm * 16 + quad * 4 + r;
                float bval = r == 0 ? bb[fm].x : (r == 1 ? bb[fm].y : (r == 2 ? bb[fm].z : bb[fm].w));
                unsigned short* row = Vto + ((size_t)(b * NH + (e >> 6)) * HD + (e & 63)) * SEQ + sbase;
#pragma unroll
                for (int fn = 0; fn < 4; fn++)
                    row[fn * 16] = f2bf(acc[fm][fn][r] + bval);
            }
    }
}

// ---------------------------------------------------------------- output-proj GEMM (fp32 out)
__global__ __launch_bounds__(256) void gemm_bt(const unsigned short* __restrict__ A,
                                               const unsigned short* __restrict__ W,
                                               const float* __restrict__ bias,
                                               float* __restrict__ out) {
    __shared__ __align__(16) unsigned short As[128 * 32];
    __shared__ __align__(16) unsigned short Bs[128 * 32];
    const int tid  = threadIdx.x;
    const int wid  = tid >> 6, lane = tid & 63;
    const int quad = lane >> 4, l15 = lane & 15;
    const int wm   = wid >> 1,  wn  = wid & 1;
    const int m0   = blockIdx.y * 128, n0 = blockIdx.x * 128;

    f32x4 acc[4][4];
#pragma unroll
    for (int i = 0; i < 4; i++)
#pragma unroll
        for (int j = 0; j < 4; j++) acc[i][j] = (f32x4)0.0f;

    const int rb = wid * 32 + (lane >> 2);
    const int cb = (lane & 3) * 8;

    for (int k0 = 0; k0 < DIMN; k0 += 32) {
#pragma unroll
        for (int i = 0; i < 2; i++) {
            const unsigned short* ga = A + (size_t)(m0 + rb + i * 16) * DIMN + k0 + cb;
            __builtin_amdgcn_global_load_lds((const __attribute__((address_space(1))) void*)ga,
                (__attribute__((address_space(3))) void*)&As[(wid * 32 + i * 16) * 32], 16, 0, 0);
            const unsigned short* gb = W + (size_t)(n0 + rb + i * 16) * DIMN + k0 + cb;
            __builtin_amdgcn_global_load_lds((const __attribute__((address_space(1))) void*)gb,
                (__attribute__((address_space(3))) void*)&Bs[(wid * 32 + i * 16) * 32], 16, 0, 0);
        }
        __syncthreads();
        bf16x8 af[4], bfr[4];
#pragma unroll
        for (int f = 0; f < 4; f++) af[f]  = *(const bf16x8*)&As[(wm * 64 + f * 16 + l15) * 32 + quad * 8];
#pragma unroll
        for (int f = 0; f < 4; f++) bfr[f] = *(const bf16x8*)&Bs[(wn * 64 + f * 16 + l15) * 32 + quad * 8];
#pragma unroll
        for (int fm = 0; fm < 4; fm++)
#pragma unroll
            for (int fn = 0; fn < 4; fn++)
                acc[fm][fn] = __builtin_amdgcn_mfma_f32_16x16x32_bf16(af[fm], bfr[fn], acc[fm][fn], 0, 0, 0);
        __syncthreads();
    }

    float bv4[4];
#pragma unroll
    for (int fn = 0; fn < 4; fn++) bv4[fn] = bias[n0 + wn * 64 + fn * 16 + l15];
#pragma unroll
    for (int fm = 0; fm < 4; fm++)
#pragma unroll
        for (int r = 0; r < 4; r++) {
            int mrow = m0 + wm * 64 + fm * 16 + quad * 4 + r;
            float* orow = out + (size_t)mrow * DIMN + n0 + wn * 64;
#pragma unroll
            for (int fn = 0; fn < 4; fn++) orow[fn * 16 + l15] = acc[fm][fn][r] + bv4[fn];
        }
}

// ---------------------------------------------------------------- flash attention v4
// grid (SEQ/256, B*NH), 4 waves x 64 q-rows each. No online max (exp2 domain,
// Q pre-scaled). S^T = K*Q^T; P^T round-trips wave-private LDS per 32-kk half
// (no barrier). V pre-transposed globally. K/V prefetched one tile ahead.
__global__ __launch_bounds__(256, 3) void attn_kernel(const unsigned short* __restrict__ Q,
                                                      const unsigned short* __restrict__ K,
                                                      const unsigned short* __restrict__ Vt,
                                                      const unsigned long long* __restrict__ M64,
                                                      unsigned short* __restrict__ Ob) {
    __shared__ __align__(16) unsigned short Ks[64 * 72];       //  9216 B
    __shared__ __align__(16) unsigned short Vs[64 * 72];       //  9216 B
    __shared__ __align__(16) unsigned short Ps[4 * 64 * 40];   // 20480 B (per-wave 64q x 32kk+8pad)

    const int tid  = threadIdx.x;
    const int wid  = tid >> 6, lane = tid & 63;
    const int quad = lane >> 4, l15 = lane & 15;
    const int bh = blockIdx.y, b = bh >> 4, h = bh & 15;
    const int q0 = blockIdx.x * 256;

    // persistent Q fragments: q = q0 + wid*64 + n*16 + l15
    bf16x8 qf[4][2];
#pragma unroll
    for (int n = 0; n < 4; n++) {
        const int qs = q0 + wid * 64 + n * 16 + l15;
#pragma unroll
        for (int dk = 0; dk < 2; dk++)
            qf[n][dk] = __builtin_bit_cast(bf16x8,
                *(const uint4*)&Q[((size_t)bh * SEQ + qs) * HD + dk * 32 + quad * 8]);
    }

    f32x4 Oa[4][4];                      // O^T: [df][n]; lane: d=df*16+quad*4+r, q=n*16+l15
#pragma unroll
    for (int i = 0; i < 4; i++)
#pragma unroll
        for (int n = 0; n < 4; n++) Oa[i][n] = (f32x4)0.0f;
    float ls[4] = {0.0f, 0.0f, 0.0f, 0.0f};

    unsigned short* Pw = &Ps[wid * 64 * 40];
    const int sr = tid >> 2;             // staging row 0..63
    const int sc = (tid & 3) * 8;        // staging col
    const unsigned short* Kg = K + (size_t)bh * SEQ * HD;
    const unsigned short* Vg = Vt + ((size_t)bh * HD + sr) * SEQ + sc;

    uint4 ka[2], va[2];
    unsigned long long mb;
#pragma unroll
    for (int i = 0; i < 2; i++) ka[i] = *(const uint4*)&Kg[(size_t)sr * HD + sc + i * 32];
#pragma unroll
    for (int i = 0; i < 2; i++) va[i] = *(const uint4*)&Vg[i * 32];
    mb = M64[b * (SEQ / 64)];

    for (int kt = 0; kt < SEQ / 64; kt++) {
#pragma unroll
        for (int i = 0; i < 2; i++) *(uint4*)&Ks[sr * 72 + sc + i * 32] = ka[i];
#pragma unroll
        for (int i = 0; i < 2; i++) *(uint4*)&Vs[sr * 72 + sc + i * 32] = va[i];
        unsigned long long mbc = mb;
        __syncthreads();

        if (kt + 1 < SEQ / 64) {         // prefetch next tile
            const int k1 = (kt + 1) * 64;
#pragma unroll
            for (int i = 0; i < 2; i++) ka[i] = *(const uint4*)&Kg[(size_t)(k1 + sr) * HD + sc + i * 32];
#pragma unroll
            for (int i = 0; i < 2; i++) va[i] = *(const uint4*)&Vg[k1 + i * 32];
            mb = M64[b * (SEQ / 64) + kt + 1];
        }

#pragma unroll
        for (int h2 = 0; h2 < 2; h2++) { // 32-kk half
            // S^T frags for kk in [h2*32, h2*32+32): A=K rows, B=Q^T
            f32x4 st[2][4];
#pragma unroll
            for (int f2 = 0; f2 < 2; f2++) {
                const int f = h2 * 2 + f2;
                bf16x8 kf0 = *(const bf16x8*)&Ks[(f * 16 + l15) * 72 + quad * 8];
                bf16x8 kf1 = *(const bf16x8*)&Ks[(f * 16 + l15) * 72 + 32 + quad * 8];
#pragma unroll
                for (int n = 0; n < 4; n++) {
                    st[f2][n] = __builtin_amdgcn_mfma_f32_16x16x32_bf16(kf0, qf[n][0], (f32x4)0.0f, 0, 0, 0);
                    st[f2][n] = __builtin_amdgcn_mfma_f32_16x16x32_bf16(kf1, qf[n][1], st[f2][n], 0, 0, 0);
                }
            }
            unsigned int mh = (unsigned int)(mbc >> (h2 * 32));
            if (mh) {                    // wave-uniform; rare
#pragma unroll
                for (int f2 = 0; f2 < 2; f2++)
#pragma unroll
                    for (int n = 0; n < 4; n++)
#pragma unroll
                        for (int r = 0; r < 4; r++) {
                            int kk = f2 * 16 + quad * 4 + r;
                            if ((mh >> kk) & 1u) st[f2][n][r] = -1e9f;
                        }
            }
            // exp2, sum, truncate-pack, write P^T half (wave-private, no barrier)
#pragma unroll
            for (int f2 = 0; f2 < 2; f2++)
#pragma unroll
                for (int n = 0; n < 4; n++) {
                    float p0 = exp2f(st[f2][n][0]);
                    float p1 = exp2f(st[f2][n][1]);
                    float p2 = exp2f(st[f2][n][2]);
                    float p3 = exp2f(st[f2][n][3]);
                    ls[n] += (p0 + p1) + (p2 + p3);
                    uint2 w;
                    w.x = pack2bf_trunc(p0, p1);
                    w.y = pack2bf_trunc(p2, p3);
                    *(uint2*)&Pw[(n * 16 + l15) * 40 + f2 * 16 + quad * 4] = w;
                }
            // O^T += V^T * P^T over this kk half
            bf16x8 pf[4];
#pragma unroll
            for (int n = 0; n < 4; n++)
                pf[n] = *(const bf16x8*)&Pw[(n * 16 + l15) * 40 + quad * 8];
#pragma unroll
            for (int df = 0; df < 4; df++) {
                bf16x8 vf = *(const bf16x8*)&Vs[(df * 16 + l15) * 72 + h2 * 32 + quad * 8];
#pragma unroll
                for (int n = 0; n < 4; n++)
                    Oa[df][n] = __builtin_amdgcn_mfma_f32_16x16x32_bf16(vf, pf[n], Oa[df][n], 0, 0, 0);
            }
        }
        __syncthreads();
    }

    float linv[4];
#pragma unroll
    for (int n = 0; n < 4; n++) {
        float l = ls[n];
        l += __shfl_xor(l, 16);
        l += __shfl_xor(l, 32);
        linv[n] = 1.0f / l;
    }

#pragma unroll
    for (int n = 0; n < 4; n++) {
        int s = q0 + wid * 64 + n * 16 + l15;
        unsigned short* orow = Ob + ((size_t)b * SEQ + s) * DIMN + h * HD + quad * 4;
#pragma unroll
        for (int df = 0; df < 4; df++) {
            uint2 w;
            w.x = pack2bf(Oa[df][n][0] * linv[n], Oa[df][n][1] * linv[n]);
            w.y = pack2bf(Oa[df][n][2] * linv[n], Oa[df][n][3] * linv[n]);
            *(uint2*)&orow[df * 16] = w;
        }
    }
}

// ---------------------------------------------------------------- launch
extern "C" void kernel_launch(void* const* d_in, const int* in_sizes, int n_in,
                              void* d_out, int out_size, void* d_ws, size_t ws_size,
                              hipStream_t stream) {
    (void)in_sizes; (void)n_in; (void)out_size; (void)ws_size;
    const float* x  = (const float*)d_in[0];
    const unsigned char* mask = (const unsigned char*)d_in[1];
    const float* q_w = (const float*)d_in[2];
    const float* q_b = (const float*)d_in[3];
    const float* k_w = (const float*)d_in[4];
    const float* k_b = (const float*)d_in[5];
    const float* v_w = (const float*)d_in[6];
    const float* v_b = (const float*)d_in[7];
    const float* o_w = (const float*)d_in[8];
    const float* o_b = (const float*)d_in[9];
    float* out = (float*)d_out;

    char* w = (char*)d_ws;
    unsigned short* xb = (unsigned short*)w;                        // 16 MiB (reused as attn output)
    unsigned short* wq = (unsigned short*)(w + (16u << 20));        // 4 x 2 MiB
    unsigned short* wk = wq + (1u << 20);
    unsigned short* wv = wk + (1u << 20);
    unsigned short* wo = wv + (1u << 20);
    float* cosT = (float*)(w + (24u << 20));                        // 256 KiB
    float* sinT = cosT + SEQ * 32;
    unsigned long long* m64 = (unsigned long long*)(w + (24u << 20) + (1u << 19)); // 1 KiB
    unsigned short* Qb  = (unsigned short*)(w + (25u << 20));       // 3 x 16 MiB
    unsigned short* Kb  = Qb + (8u << 20);
    unsigned short* Vtb = Kb + (8u << 20);
    unsigned short* Ob  = xb;                                       // reuse x's slot

    cast_bf16_kernel<<<dim3(MROWS * DIMN / 2048), 256, 0, stream>>>(x, xb, MROWS * DIMN);
    cast4_kernel<<<dim3(DIMN * DIMN / 2048, 4), 256, 0, stream>>>(q_w, k_w, v_w, o_w, wq, wk, wv, wo);
    rope_tables_kernel<<<dim3(SEQ * 32 / 256), 256, 0, stream>>>(cosT, sinT);
    mask64_kernel<<<dim3(1), 128, 0, stream>>>(mask, m64);

    gemm_qkvt<<<dim3(24, 64), 256, 0, stream>>>(xb, wq, wk, wv, q_b, k_b, v_b,
                                                Qb, Kb, Vtb, cosT, sinT);

    attn_kernel<<<dim3(SEQ / 256, BATCH * NH), 256, 0, stream>>>(Qb, Kb, Vtb, m64, Ob);

    gemm_bt<<<dim3(DIMN / 128, MROWS / 128), 256, 0, stream>>>(Ob, wo, o_b, out);
}

// Round 5
// 369.431 us; speedup vs baseline: 1.2660x; 1.2660x over previous
//
#include <hip/hip_runtime.h>
#include <stdint.h>

#define SEQ   2048
#define BATCH 4
#define NH    16
#define HD    64
#define DIMN  1024
#define MROWS (BATCH*SEQ)   // 8192

typedef __attribute__((ext_vector_type(8))) short          bf16x8;
typedef __attribute__((ext_vector_type(8))) unsigned short ushort8;
typedef __attribute__((ext_vector_type(4))) float          f32x4;

static __device__ __forceinline__ unsigned short f2bf(float f) {
    unsigned int u = __builtin_bit_cast(unsigned int, f);
    u += 0x7fffu + ((u >> 16) & 1u);          // RNE
    return (unsigned short)(u >> 16);
}
// RNE-ish (round-half-up) pack: 3 ops
static __device__ __forceinline__ unsigned int pack2bf(float lo, float hi) {
    unsigned int a = __builtin_bit_cast(unsigned int, lo) + 0x8000u;
    unsigned int b = __builtin_bit_cast(unsigned int, hi) + 0x8000u;
    return __builtin_amdgcn_perm(b, a, 0x07060302u);
}
// truncating pack: 1 op (P in [0,1], rel err <= 2^-8, fine for softmax weights)
static __device__ __forceinline__ unsigned int pack2bf_trunc(float lo, float hi) {
    return __builtin_amdgcn_perm(__builtin_bit_cast(unsigned int, hi),
                                 __builtin_bit_cast(unsigned int, lo), 0x07060302u);
}

// ---------------------------------------------------------------- fused prologue
// blockIdx.x: [0,4096) x-cast; [4096,6144) 4 weight casts; [6144,6400) rope
// tables; 6400 mask->u64. All branches wave-uniform.
__global__ __launch_bounds__(256) void prologue_kernel(
        const float* __restrict__ x,
        const float* __restrict__ qw, const float* __restrict__ kw,
        const float* __restrict__ vw, const float* __restrict__ ow,
        unsigned short* __restrict__ xb,
        unsigned short* __restrict__ wq, unsigned short* __restrict__ wk,
        unsigned short* __restrict__ wv, unsigned short* __restrict__ wo,
        float* __restrict__ cosT, float* __restrict__ sinT,
        const unsigned char* __restrict__ mask, unsigned long long* __restrict__ m64) {
    const int bx = blockIdx.x, tid = threadIdx.x;
    if (bx < 4096 + 2048) {
        const float* s; unsigned short* d; int i;
        if (bx < 4096) { s = x; d = xb; i = bx * 2048 + tid * 8; }
        else {
            int wb = bx - 4096;
            int wsel = wb >> 9;
            s = wsel == 0 ? qw : (wsel == 1 ? kw : (wsel == 2 ? vw : ow));
            d = wsel == 0 ? wq : (wsel == 1 ? wk : (wsel == 2 ? wv : wo));
            i = (wb & 511) * 2048 + tid * 8;
        }
        float4 a = *(const float4*)(s + i);
        float4 b = *(const float4*)(s + i + 4);
        ushort8 o;
        o[0]=f2bf(a.x); o[1]=f2bf(a.y); o[2]=f2bf(a.z); o[3]=f2bf(a.w);
        o[4]=f2bf(b.x); o[5]=f2bf(b.y); o[6]=f2bf(b.z); o[7]=f2bf(b.w);
        *(ushort8*)(d + i) = o;
    } else if (bx < 6400) {
        int idx = (bx - 6144) * 256 + tid;        // SEQ*32
        int s = idx >> 5, j = idx & 31;
        float t = (float)(2 * j) / 64.0f;
        float freq = 1.0f / powf(10000.0f, t);
        float ang  = (float)s * freq;
        cosT[idx] = cosf(ang);
        sinT[idx] = sinf(ang);
    } else {
        if (tid < 128) {
            int b = tid >> 5, kt = tid & 31;
            const unsigned char* p = mask + b * SEQ + kt * 64;
            unsigned long long v = 0;
            for (int j = 0; j < 64; j++) v |= (unsigned long long)(p[j] != 0) << j;
            m64[tid] = v;
        }
    }
}

// ---------------------------------------------------------------- fused Q,K,V^T GEMM
// blockIdx.x: [0..7]=Q, [8..15]=K (both +RoPE, out [B,H,S,D]), [16..23]=V^T
// (out [B,H,D,S]). Q pre-scaled by 0.125*log2e for exp2-domain softmax.
__global__ __launch_bounds__(256) void gemm_qkvt(const unsigned short* __restrict__ X,
        const unsigned short* __restrict__ Wq, const unsigned short* __restrict__ Wk,
        const unsigned short* __restrict__ Wv,
        const float* __restrict__ bq, const float* __restrict__ bk, const float* __restrict__ bv,
        unsigned short* __restrict__ Qo, unsigned short* __restrict__ Ko, unsigned short* __restrict__ Vto,
        const float* __restrict__ cosT, const float* __restrict__ sinT) {
    __shared__ __align__(16) unsigned short As[128 * 32];
    __shared__ __align__(16) unsigned short Bs[128 * 32];
    const int which = blockIdx.x >> 3;
    const int tid  = threadIdx.x;
    const int wid  = tid >> 6, lane = tid & 63;
    const int quad = lane >> 4, l15 = lane & 15;
    const int wm   = wid >> 1,  wn  = wid & 1;

    const unsigned short *Ag, *Bg;
    int m0, n0;
    if (which < 2) {
        m0 = blockIdx.y * 128;                 // token rows
        n0 = (blockIdx.x & 7) * 128;           // embed cols
        Ag = X;  Bg = which == 0 ? Wq : Wk;
    } else {
        m0 = (blockIdx.x & 7) * 128;           // e rows
        n0 = blockIdx.y * 128;                 // token rows
        Ag = Wv; Bg = X;
    }

    f32x4 acc[4][4];
#pragma unroll
    for (int i = 0; i < 4; i++)
#pragma unroll
        for (int j = 0; j < 4; j++) acc[i][j] = (f32x4)0.0f;

    const int rb = wid * 32 + (lane >> 2);
    const int cb = (lane & 3) * 8;

    for (int k0 = 0; k0 < DIMN; k0 += 32) {
#pragma unroll
        for (int i = 0; i < 2; i++) {
            const unsigned short* ga = Ag + (size_t)(m0 + rb + i * 16) * DIMN + k0 + cb;
            __builtin_amdgcn_global_load_lds((const __attribute__((address_space(1))) void*)ga,
                (__attribute__((address_space(3))) void*)&As[(wid * 32 + i * 16) * 32], 16, 0, 0);
            const unsigned short* gb = Bg + (size_t)(n0 + rb + i * 16) * DIMN + k0 + cb;
            __builtin_amdgcn_global_load_lds((const __attribute__((address_space(1))) void*)gb,
                (__attribute__((address_space(3))) void*)&Bs[(wid * 32 + i * 16) * 32], 16, 0, 0);
        }
        __syncthreads();
        bf16x8 af[4], bfr[4];
#pragma unroll
        for (int f = 0; f < 4; f++) af[f]  = *(const bf16x8*)&As[(wm * 64 + f * 16 + l15) * 32 + quad * 8];
#pragma unroll
        for (int f = 0; f < 4; f++) bfr[f] = *(const bf16x8*)&Bs[(wn * 64 + f * 16 + l15) * 32 + quad * 8];
#pragma unroll
        for (int fm = 0; fm < 4; fm++)
#pragma unroll
            for (int fn = 0; fn < 4; fn++)
                acc[fm][fn] = __builtin_amdgcn_mfma_f32_16x16x32_bf16(af[fm], bfr[fn], acc[fm][fn], 0, 0, 0);
        __syncthreads();
    }

    if (which < 2) {                            // Q or K: +bias, scale, RoPE, [B,H,S,D]
        const float* bias   = which == 0 ? bq : bk;
        unsigned short* Out = which == 0 ? Qo : Ko;
        const float scale = which == 0 ? 0.18033688011112042f : 1.0f;  // 0.125*log2e
        float bv4[4];
#pragma unroll
        for (int fn = 0; fn < 4; fn++) bv4[fn] = bias[n0 + wn * 64 + fn * 16 + l15];
        const int h = (n0 >> 6) + wn;
#pragma unroll
        for (int fm = 0; fm < 4; fm++)
#pragma unroll
            for (int r = 0; r < 4; r++) {
                int mrow = m0 + wm * 64 + fm * 16 + quad * 4 + r;
                int b = mrow >> 11, s = mrow & (SEQ - 1);
                unsigned short* orow = Out + ((size_t)(b * NH + h) * SEQ + s) * HD;
                float v0 = (acc[fm][0][r] + bv4[0]) * scale;
                float v1 = (acc[fm][1][r] + bv4[1]) * scale;
                float v2 = (acc[fm][2][r] + bv4[2]) * scale;
                float v3 = (acc[fm][3][r] + bv4[3]) * scale;
                int d0 = l15, d1 = 16 + l15;
                float c0 = cosT[s * 32 + d0], s0 = sinT[s * 32 + d0];
                float c1 = cosT[s * 32 + d1], s1 = sinT[s * 32 + d1];
                orow[d0]      = f2bf(v0 * c0 - v2 * s0);
                orow[d0 + 32] = f2bf(v0 * s0 + v2 * c0);
                orow[d1]      = f2bf(v1 * c1 - v3 * s1);
                orow[d1 + 32] = f2bf(v1 * s1 + v3 * c1);
            }
    } else {                                    // V^T: [B,H,D,S]
        float4 bb[4];
#pragma unroll
        for (int fm = 0; fm < 4; fm++)
            bb[fm] = *(const float4*)&bv[m0 + wm * 64 + fm * 16 + quad * 4];
        const int b     = n0 >> 11;
        const int sbase = (n0 & (SEQ - 1)) + wn * 64 + l15;
#pragma unroll
        for (int fm = 0; fm < 4; fm++)
#pragma unroll
            for (int r = 0; r < 4; r++) {
                int e = m0 + wm * 64 + fm * 16 + quad * 4 + r;
                float bval = r == 0 ? bb[fm].x : (r == 1 ? bb[fm].y : (r == 2 ? bb[fm].z : bb[fm].w));
                unsigned short* row = Vto + ((size_t)(b * NH + (e >> 6)) * HD + (e & 63)) * SEQ + sbase;
#pragma unroll
                for (int fn = 0; fn < 4; fn++)
                    row[fn * 16] = f2bf(acc[fm][fn][r] + bval);
            }
    }
}

// ---------------------------------------------------------------- output-proj GEMM (fp32 out)
__global__ __launch_bounds__(256) void gemm_bt(const unsigned short* __restrict__ A,
                                               const unsigned short* __restrict__ W,
                                               const float* __restrict__ bias,
                                               float* __restrict__ out) {
    __shared__ __align__(16) unsigned short As[128 * 32];
    __shared__ __align__(16) unsigned short Bs[128 * 32];
    const int tid  = threadIdx.x;
    const int wid  = tid >> 6, lane = tid & 63;
    const int quad = lane >> 4, l15 = lane & 15;
    const int wm   = wid >> 1,  wn  = wid & 1;
    const int m0   = blockIdx.y * 128, n0 = blockIdx.x * 128;

    f32x4 acc[4][4];
#pragma unroll
    for (int i = 0; i < 4; i++)
#pragma unroll
        for (int j = 0; j < 4; j++) acc[i][j] = (f32x4)0.0f;

    const int rb = wid * 32 + (lane >> 2);
    const int cb = (lane & 3) * 8;

    for (int k0 = 0; k0 < DIMN; k0 += 32) {
#pragma unroll
        for (int i = 0; i < 2; i++) {
            const unsigned short* ga = A + (size_t)(m0 + rb + i * 16) * DIMN + k0 + cb;
            __builtin_amdgcn_global_load_lds((const __attribute__((address_space(1))) void*)ga,
                (__attribute__((address_space(3))) void*)&As[(wid * 32 + i * 16) * 32], 16, 0, 0);
            const unsigned short* gb = W + (size_t)(n0 + rb + i * 16) * DIMN + k0 + cb;
            __builtin_amdgcn_global_load_lds((const __attribute__((address_space(1))) void*)gb,
                (__attribute__((address_space(3))) void*)&Bs[(wid * 32 + i * 16) * 32], 16, 0, 0);
        }
        __syncthreads();
        bf16x8 af[4], bfr[4];
#pragma unroll
        for (int f = 0; f < 4; f++) af[f]  = *(const bf16x8*)&As[(wm * 64 + f * 16 + l15) * 32 + quad * 8];
#pragma unroll
        for (int f = 0; f < 4; f++) bfr[f] = *(const bf16x8*)&Bs[(wn * 64 + f * 16 + l15) * 32 + quad * 8];
#pragma unroll
        for (int fm = 0; fm < 4; fm++)
#pragma unroll
            for (int fn = 0; fn < 4; fn++)
                acc[fm][fn] = __builtin_amdgcn_mfma_f32_16x16x32_bf16(af[fm], bfr[fn], acc[fm][fn], 0, 0, 0);
        __syncthreads();
    }

    float bv4[4];
#pragma unroll
    for (int fn = 0; fn < 4; fn++) bv4[fn] = bias[n0 + wn * 64 + fn * 16 + l15];
#pragma unroll
    for (int fm = 0; fm < 4; fm++)
#pragma unroll
        for (int r = 0; r < 4; r++) {
            int mrow = m0 + wm * 64 + fm * 16 + quad * 4 + r;
            float* orow = out + (size_t)mrow * DIMN + n0 + wn * 64;
#pragma unroll
            for (int fn = 0; fn < 4; fn++) orow[fn * 16 + l15] = acc[fm][fn][r] + bv4[fn];
        }
}

// ---------------------------------------------------------------- flash attention v5
// R3 structure (grid (SEQ/128, B*NH), 4 waves x 32 q-rows) + halved-kk P
// round-trip (smaller st live range + LDS 28.7 KB -> 5 blocks/CU) + register
// prefetch of next K/V tile. No online max (exp2 domain, Q pre-scaled).
__global__ __launch_bounds__(256, 4) void attn_kernel(const unsigned short* __restrict__ Q,
                                                      const unsigned short* __restrict__ K,
                                                      const unsigned short* __restrict__ Vt,
                                                      const unsigned long long* __restrict__ M64,
                                                      unsigned short* __restrict__ Ob) {
    __shared__ __align__(16) unsigned short Ks[64 * 72];       //  9216 B
    __shared__ __align__(16) unsigned short Vs[64 * 72];       //  9216 B
    __shared__ __align__(16) unsigned short Ps[4 * 32 * 40];   // 10240 B (wave-private 32q x 32kk+8pad)

    const int tid  = threadIdx.x;
    const int wid  = tid >> 6, lane = tid & 63;
    const int quad = lane >> 4, l15 = lane & 15;
    const int bh = blockIdx.y, b = bh >> 4, h = bh & 15;
    const int q0 = blockIdx.x * 128;

    // persistent Q fragments: q = q0 + wid*32 + n*16 + l15
    bf16x8 qf[2][2];
#pragma unroll
    for (int n = 0; n < 2; n++) {
        const int qs = q0 + wid * 32 + n * 16 + l15;
#pragma unroll
        for (int dk = 0; dk < 2; dk++)
            qf[n][dk] = __builtin_bit_cast(bf16x8,
                *(const uint4*)&Q[((size_t)bh * SEQ + qs) * HD + dk * 32 + quad * 8]);
    }

    f32x4 Oa[4][2];                      // O^T: [df][n]; lane: d=df*16+quad*4+r, q=n*16+l15
#pragma unroll
    for (int i = 0; i < 4; i++)
#pragma unroll
        for (int n = 0; n < 2; n++) Oa[i][n] = (f32x4)0.0f;
    float ls[2] = {0.0f, 0.0f};

    unsigned short* Pw = &Ps[wid * 32 * 40];
    const int sr = tid >> 2;             // staging row 0..63
    const int sc = (tid & 3) * 8;        // staging col
    const unsigned short* Kg = K + (size_t)bh * SEQ * HD;
    const unsigned short* Vg = Vt + ((size_t)bh * HD + sr) * SEQ + sc;

    uint4 ka[2], va[2];
    unsigned long long mb;
#pragma unroll
    for (int i = 0; i < 2; i++) ka[i] = *(const uint4*)&Kg[(size_t)sr * HD + sc + i * 32];
#pragma unroll
    for (int i = 0; i < 2; i++) va[i] = *(const uint4*)&Vg[i * 32];
    mb = M64[b * (SEQ / 64)];

    for (int kt = 0; kt < SEQ / 64; kt++) {
#pragma unroll
        for (int i = 0; i < 2; i++) *(uint4*)&Ks[sr * 72 + sc + i * 32] = ka[i];
#pragma unroll
        for (int i = 0; i < 2; i++) *(uint4*)&Vs[sr * 72 + sc + i * 32] = va[i];
        unsigned long long mbc = mb;
        __syncthreads();

        if (kt + 1 < SEQ / 64) {         // prefetch next tile into registers
            const int k1 = (kt + 1) * 64;
#pragma unroll
            for (int i = 0; i < 2; i++) ka[i] = *(const uint4*)&Kg[(size_t)(k1 + sr) * HD + sc + i * 32];
#pragma unroll
            for (int i = 0; i < 2; i++) va[i] = *(const uint4*)&Vg[k1 + i * 32];
            mb = M64[b * (SEQ / 64) + kt + 1];
        }

#pragma unroll
        for (int h2 = 0; h2 < 2; h2++) {      // 32-kk half
            f32x4 st[2][2];
#pragma unroll
            for (int f2 = 0; f2 < 2; f2++) {
                const int f = h2 * 2 + f2;
                bf16x8 kf0 = *(const bf16x8*)&Ks[(f * 16 + l15) * 72 + quad * 8];
                bf16x8 kf1 = *(const bf16x8*)&Ks[(f * 16 + l15) * 72 + 32 + quad * 8];
#pragma unroll
                for (int n = 0; n < 2; n++) {
                    st[f2][n] = __builtin_amdgcn_mfma_f32_16x16x32_bf16(kf0, qf[n][0], (f32x4)0.0f, 0, 0, 0);
                    st[f2][n] = __builtin_amdgcn_mfma_f32_16x16x32_bf16(kf1, qf[n][1], st[f2][n], 0, 0, 0);
                }
            }
            unsigned int mh = (unsigned int)(mbc >> (h2 * 32));
            if (mh) {                         // wave-uniform; rare
#pragma unroll
                for (int f2 = 0; f2 < 2; f2++)
#pragma unroll
                    for (int n = 0; n < 2; n++)
#pragma unroll
                        for (int r = 0; r < 4; r++) {
                            int kk = f2 * 16 + quad * 4 + r;
                            if ((mh >> kk) & 1u) st[f2][n][r] = -1e9f;
                        }
            }
            // exp2, sum, pack, wave-private P^T half round-trip (no barrier)
#pragma unroll
            for (int f2 = 0; f2 < 2; f2++)
#pragma unroll
                for (int n = 0; n < 2; n++) {
                    float p0 = exp2f(st[f2][n][0]);
                    float p1 = exp2f(st[f2][n][1]);
                    float p2 = exp2f(st[f2][n][2]);
                    float p3 = exp2f(st[f2][n][3]);
                    ls[n] += (p0 + p1) + (p2 + p3);
                    uint2 w;
                    w.x = pack2bf_trunc(p0, p1);
                    w.y = pack2bf_trunc(p2, p3);
                    *(uint2*)&Pw[(n * 16 + l15) * 40 + f2 * 16 + quad * 4] = w;
                }
            bf16x8 pf[2];
#pragma unroll
            for (int n = 0; n < 2; n++)
                pf[n] = *(const bf16x8*)&Pw[(n * 16 + l15) * 40 + quad * 8];
#pragma unroll
            for (int df = 0; df < 4; df++) {
                bf16x8 vf = *(const bf16x8*)&Vs[(df * 16 + l15) * 72 + h2 * 32 + quad * 8];
#pragma unroll
                for (int n = 0; n < 2; n++)
                    Oa[df][n] = __builtin_amdgcn_mfma_f32_16x16x32_bf16(vf, pf[n], Oa[df][n], 0, 0, 0);
            }
        }
        __syncthreads();
    }

    float linv[2];
#pragma unroll
    for (int n = 0; n < 2; n++) {
        float l = ls[n];
        l += __shfl_xor(l, 16);
        l += __shfl_xor(l, 32);
        linv[n] = 1.0f / l;
    }

#pragma unroll
    for (int n = 0; n < 2; n++) {
        int s = q0 + wid * 32 + n * 16 + l15;
        unsigned short* orow = Ob + ((size_t)b * SEQ + s) * DIMN + h * HD + quad * 4;
#pragma unroll
        for (int df = 0; df < 4; df++) {
            uint2 w;
            w.x = pack2bf(Oa[df][n][0] * linv[n], Oa[df][n][1] * linv[n]);
            w.y = pack2bf(Oa[df][n][2] * linv[n], Oa[df][n][3] * linv[n]);
            *(uint2*)&orow[df * 16] = w;
        }
    }
}

// ---------------------------------------------------------------- launch
extern "C" void kernel_launch(void* const* d_in, const int* in_sizes, int n_in,
                              void* d_out, int out_size, void* d_ws, size_t ws_size,
                              hipStream_t stream) {
    (void)in_sizes; (void)n_in; (void)out_size; (void)ws_size;
    const float* x  = (const float*)d_in[0];
    const unsigned char* mask = (const unsigned char*)d_in[1];
    const float* q_w = (const float*)d_in[2];
    const float* q_b = (const float*)d_in[3];
    const float* k_w = (const float*)d_in[4];
    const float* k_b = (const float*)d_in[5];
    const float* v_w = (const float*)d_in[6];
    const float* v_b = (const float*)d_in[7];
    const float* o_w = (const float*)d_in[8];
    const float* o_b = (const float*)d_in[9];
    float* out = (float*)d_out;

    char* w = (char*)d_ws;
    unsigned short* xb = (unsigned short*)w;                        // 16 MiB (reused as attn output)
    unsigned short* wq = (unsigned short*)(w + (16u << 20));        // 4 x 2 MiB
    unsigned short* wk = wq + (1u << 20);
    unsigned short* wv = wk + (1u << 20);
    unsigned short* wo = wv + (1u << 20);
    float* cosT = (float*)(w + (24u << 20));                        // 256 KiB
    float* sinT = cosT + SEQ * 32;
    unsigned long long* m64 = (unsigned long long*)(w + (24u << 20) + (1u << 19)); // 1 KiB
    unsigned short* Qb  = (unsigned short*)(w + (25u << 20));       // 3 x 16 MiB
    unsigned short* Kb  = Qb + (8u << 20);
    unsigned short* Vtb = Kb + (8u << 20);
    unsigned short* Ob  = xb;                                       // reuse x's slot

    prologue_kernel<<<dim3(6401), 256, 0, stream>>>(x, q_w, k_w, v_w, o_w,
                                                    xb, wq, wk, wv, wo,
                                                    cosT, sinT, mask, m64);

    gemm_qkvt<<<dim3(24, 64), 256, 0, stream>>>(xb, wq, wk, wv, q_b, k_b, v_b,
                                                Qb, Kb, Vtb, cosT, sinT);

    attn_kernel<<<dim3(SEQ / 128, BATCH * NH), 256, 0, stream>>>(Qb, Kb, Vtb, m64, Ob);

    gemm_bt<<<dim3(DIMN / 128, MROWS / 128), 256, 0, stream>>>(Ob, wo, o_b, out);
}